// Round 4
// baseline (207.894 us; speedup 1.0000x reference)
//
#include <hip/hip_runtime.h>

typedef __attribute__((ext_vector_type(8))) short short8;
typedef __attribute__((ext_vector_type(4))) float f32x4;
typedef __attribute__((ext_vector_type(16))) float f32x16;
typedef __attribute__((ext_vector_type(2))) unsigned int uint2v;

#define EMB 768
#define SEQ 4096
#define NH 12
#define HD 64
// 8 * log2(e): folds the score scale AND the exp->exp2 conversion into Q
#define QSCALE 11.541560327111707f

#define GLOBAL_AS __attribute__((address_space(1)))
#define LDS_AS __attribute__((address_space(3)))

__device__ inline ushort f2bf(float v) {
  union { float f; unsigned int u; } x; x.f = v;
  unsigned int r = x.u + 0x7fffu + ((x.u >> 16) & 1u);
  return (ushort)(r >> 16);
}
__device__ inline float bf2f(ushort u) {
  union { float f; unsigned int u32; } x; x.u32 = ((unsigned int)u) << 16;
  return x.f;
}

// pack two f32 -> one dword of 2 bf16 (RNE), lo=a hi=b
__device__ inline int cvt_pk_bf16(float a, float b) {
  int r;
  asm("v_cvt_pk_bf16_f32 %0, %1, %2" : "=v"(r) : "v"(a), "v"(b));
  return r;
}
// 3-input max in one VALU op
__device__ inline float max3f(float a, float b, float c) {
  float r;
  asm("v_max3_f32 %0, %1, %2, %3" : "=v"(r) : "v"(a), "v"(b), "v"(c));
  return r;
}
// permlane32_swap via BUILTIN (not raw asm): compiler handles the CDNA4
// cross-lane hazard wait-states and tied-register allocation.
__device__ inline void pswap(int& a, int& b) {
  uint2v r = __builtin_amdgcn_permlane32_swap((unsigned)a, (unsigned)b, false, false);
  a = (int)r.x;
  b = (int)r.y;
}

// merged split (float4-vectorized): x -> xh/xl, qkv_w -> qwh/qwl, out_w -> owh
__global__ void split_all(const float* __restrict__ x, const float* __restrict__ qw,
                          const float* __restrict__ ow,
                          ushort* __restrict__ xh, ushort* __restrict__ xl,
                          ushort* __restrict__ qwh, ushort* __restrict__ qwl,
                          ushort* __restrict__ owh, int n14, int n24) {
  int i = blockIdx.x * blockDim.x + threadIdx.x;
  const float4* src;
  ushort4 *dh, *dl;
  int j;
  if (i < n14) {
    src = (const float4*)x; dh = (ushort4*)xh; dl = (ushort4*)xl; j = i;
  } else if (i < n14 + n24) {
    src = (const float4*)qw; dh = (ushort4*)qwh; dl = (ushort4*)qwl; j = i - n14;
  } else {
    j = i - n14 - n24;
    float4 v = ((const float4*)ow)[j];
    ushort4 h = {f2bf(v.x), f2bf(v.y), f2bf(v.z), f2bf(v.w)};
    ((ushort4*)owh)[j] = h;
    return;
  }
  float4 v = src[j];
  ushort4 h = {f2bf(v.x), f2bf(v.y), f2bf(v.z), f2bf(v.w)};
  ushort4 l = {f2bf(v.x - bf2f(h.x)), f2bf(v.y - bf2f(h.y)),
               f2bf(v.z - bf2f(h.z)), f2bf(v.w - bf2f(h.w))};
  dh[j] = h;
  dl[j] = l;
}

// C[m,n] = sum_k A[m,k]*B[n,k] (both K-contiguous), global_load_lds staging,
// double-buffered K-loop. mode 1: QKV scatter; Q,K 3-term; V (bn>=12) 1-term.
// mode 2: 1-term plain bf16, C += bias -> Cout fp32 (out-proj).
__global__ __launch_bounds__(256, 2) void gemm_bt_split(
    const ushort* __restrict__ Ah, const ushort* __restrict__ Al,
    const ushort* __restrict__ Bh, const ushort* __restrict__ Bl,
    int M, int N, int K, int mode,
    float* __restrict__ Cout, const float* __restrict__ bias,
    ushort* __restrict__ Qh, ushort* __restrict__ Ql,
    ushort* __restrict__ Kh, ushort* __restrict__ Kl,
    ushort* __restrict__ Vt) {
  __shared__ ushort smem[2][4 * 128 * 32];  // 2 x 32KB staging buffers

  const int tid = threadIdx.x;
  const int lane = tid & 63;
  const int w = tid >> 6;
  const int wm = w >> 1, wn = w & 1;
  const int col = lane & 15, quad = lane >> 4;
  const int bm = blockIdx.x, bn = blockIdx.y;

  const bool oneterm = (mode == 2) || (mode == 1 && bn >= 12);
  const bool skipdma = oneterm && (w == 1 || w == 3);  // lo tiles unused

  const ushort* gsrc = (w == 0)   ? Ah + (size_t)bm * 128 * K
                       : (w == 1) ? Al + (size_t)bm * 128 * K
                       : (w == 2) ? Bh + (size_t)bn * 128 * K
                                  : Bl + (size_t)bn * 128 * K;
  const int loff = w * 4096;  // matrix offset inside a buffer
  const ushort* g0 = gsrc + (size_t)(lane >> 2) * K + (lane & 3) * 8;

  f32x4 acc[4][4];
  const f32x4 zz = {0.f, 0.f, 0.f, 0.f};
#pragma unroll
  for (int i = 0; i < 4; ++i)
#pragma unroll
    for (int j = 0; j < 4; ++j) acc[i][j] = zz;

#define GSTAGE(b, kt)                                                       \
  if (!skipdma) {                                                           \
    _Pragma("unroll") for (int i = 0; i < 8; ++i) {                         \
      __builtin_amdgcn_global_load_lds(                                     \
          (const GLOBAL_AS unsigned int*)(g0 + (size_t)i * 16 * K + (kt)),  \
          (LDS_AS unsigned int*)(&smem[b][loff + i * 512]), 16, 0, 0);      \
    }                                                                       \
  }

  GSTAGE(0, 0);
  const int nk = K / 32;
  for (int it = 0; it < nk; ++it) {
    const int buf = it & 1;
    asm volatile("s_waitcnt vmcnt(0)" ::: "memory");
    __syncthreads();
    if (it + 1 < nk) GSTAGE(buf ^ 1, (it + 1) * 32);

    const ushort* sAh = &smem[buf][0];
    const ushort* sAl = &smem[buf][4096];
    const ushort* sBh = &smem[buf][8192];
    const ushort* sBl = &smem[buf][12288];

    if (oneterm) {
      short8 fah[4], fbh[4];
#pragma unroll
      for (int t = 0; t < 4; ++t) {
        fah[t] = *(const short8*)(&sAh[(wm * 64 + t * 16 + col) * 32 + quad * 8]);
        fbh[t] = *(const short8*)(&sBh[(wn * 64 + t * 16 + col) * 32 + quad * 8]);
      }
#pragma unroll
      for (int tm = 0; tm < 4; ++tm)
#pragma unroll
        for (int tn = 0; tn < 4; ++tn)
          acc[tm][tn] = __builtin_amdgcn_mfma_f32_16x16x32_bf16(fah[tm], fbh[tn], acc[tm][tn], 0, 0, 0);
    } else {
      short8 fah[4], fal[4], fbh[4], fbl[4];
#pragma unroll
      for (int t = 0; t < 4; ++t) {
        int ra = (wm * 64 + t * 16 + col) * 32 + quad * 8;
        fah[t] = *(const short8*)(&sAh[ra]);
        fal[t] = *(const short8*)(&sAl[ra]);
        int rb = (wn * 64 + t * 16 + col) * 32 + quad * 8;
        fbh[t] = *(const short8*)(&sBh[rb]);
        fbl[t] = *(const short8*)(&sBl[rb]);
      }
#pragma unroll
      for (int tm = 0; tm < 4; ++tm)
#pragma unroll
        for (int tn = 0; tn < 4; ++tn) {
          acc[tm][tn] = __builtin_amdgcn_mfma_f32_16x16x32_bf16(fah[tm], fbh[tn], acc[tm][tn], 0, 0, 0);
          acc[tm][tn] = __builtin_amdgcn_mfma_f32_16x16x32_bf16(fah[tm], fbl[tn], acc[tm][tn], 0, 0, 0);
          acc[tm][tn] = __builtin_amdgcn_mfma_f32_16x16x32_bf16(fal[tm], fbh[tn], acc[tm][tn], 0, 0, 0);
        }
    }
  }

  const int m_base = bm * 128 + wm * 64;
  const int n_base = bn * 128 + wn * 64;

  if (mode != 1) {
#pragma unroll
    for (int tm = 0; tm < 4; ++tm)
#pragma unroll
      for (int tn = 0; tn < 4; ++tn) {
        int gn = n_base + tn * 16 + col;
        float b = bias[gn];
#pragma unroll
        for (int rr = 0; rr < 4; ++rr) {
          int gm = m_base + tm * 16 + quad * 4 + rr;
          Cout[(size_t)gm * N + gn] = acc[tm][tn][rr] + b;
        }
      }
  } else {
    int reg = bn / 6;  // 0:Q 1:K 2:V (uniform per block)
    if (reg < 2) {
#pragma unroll
      for (int tm = 0; tm < 4; ++tm)
#pragma unroll
        for (int tn = 0; tn < 4; ++tn) {
          int el = (bn % 6) * 128 + wn * 64 + tn * 16 + col;  // 0..767
          int hh = el >> 6, dd = el & 63;
#pragma unroll
          for (int rr = 0; rr < 4; ++rr) {
            int gm = m_base + tm * 16 + quad * 4 + rr;
            float v = acc[tm][tn][rr];
            if (reg == 0) {
              v *= QSCALE;
              ushort hi = f2bf(v);
              size_t idx = ((size_t)hh * SEQ + gm) * HD + dd;  // Q unswizzled
              Qh[idx] = hi;
              Ql[idx] = f2bf(v - bf2f(hi));
            } else {
              // K swizzled: chunk' = chunk ^ (key&7) for attn's DMA image
              ushort hi = f2bf(v);
              int pc = ((dd >> 3) ^ (gm & 7)) & 7;
              size_t idx = ((size_t)hh * SEQ + gm) * HD + pc * 8 + (dd & 7);
              Kh[idx] = hi;
              Kl[idx] = f2bf(v - bf2f(hi));
            }
          }
        }
    } else {
      // ---- V: LDS transpose -> coalesced swizzled stores ----
      __syncthreads();
      ushort* vt_tile = &smem[0][0];  // 128*128 ushort = 32KB
#pragma unroll
      for (int tm = 0; tm < 4; ++tm)
#pragma unroll
        for (int tn = 0; tn < 4; ++tn) {
          int el = wn * 64 + tn * 16 + col;
#pragma unroll
          for (int rr = 0; rr < 4; ++rr) {
            int seq = wm * 64 + tm * 16 + quad * 4 + rr;
            int cc = (((seq >> 3) & 7) ^ (el & 7)) & 7;
            vt_tile[el * 128 + (seq & 64) + cc * 8 + (seq & 7)] = f2bf(acc[tm][tn][rr]);
          }
        }
      __syncthreads();
      int el = tid >> 1;
      int elg = (bn % 6) * 128 + el;
      int hh = elg >> 6, dd = elg & 63;
      ushort* grow = Vt + (size_t)(hh * HD + dd) * SEQ + bm * 128;
#pragma unroll
      for (int i = 0; i < 8; ++i) {
        int c = ((tid & 1) * 8 + i + el) & 15;
        *(uint4*)(grow + c * 8) = *(const uint4*)(&vt_tile[el * 128 + c * 8]);
      }
    }
  }
}

// Flash attention R15 = R14 (32x32 T12 structure, verified) +
//  - s accumulator split into two independent 6-MFMA chains (halves the
//    dependent-MFMA critical path), merged with 16 adds
//  - s_setprio(1) around the MFMA clusters (T5)
//  - v_max3_f32 row-max tree (15 -> 8 ops)
//  - final-iteration DMA prefetch guarded (no in-flight DMA at endpgm)
__global__ __launch_bounds__(256, 3) void attn_k(
    const ushort* __restrict__ Qh, const ushort* __restrict__ Ql,
    const ushort* __restrict__ Kh, const ushort* __restrict__ Kl,
    const ushort* __restrict__ Vt, ushort* __restrict__ Ch) {
  // regions (ushort idx): KH[2][4096] @0, KL[2][4096] @8192, VT[2][4096] @16384
  __shared__ __attribute__((aligned(128))) ushort smem[6 * 4096];  // 48KB

  const int tid = threadIdx.x, lane = tid & 63, w = tid >> 6;
  const int wq = w >> 1, wk = w & 1;
  const int qc = lane & 31, hl = lane >> 5;
  const int head = blockIdx.y;
  const int qb = blockIdx.x * 64 + wq * 32;

  // ---- Q fragments (B-operand): B[n=query qc][k = d*16 + hl*8 + j]
  const ushort* qh_base = Qh + ((size_t)head * SEQ + qb + qc) * HD + hl * 8;
  const ushort* ql_base = Ql + ((size_t)head * SEQ + qb + qc) * HD + hl * 8;
  short8 fqh[4], fql[4];
#pragma unroll
  for (int d = 0; d < 4; ++d) {
    fqh[d] = *(const short8*)(qh_base + d * 16);
    fql[d] = *(const short8*)(ql_base + d * 16);
  }

  // ---- staging (identical DMA pattern to R14)
  const ushort* khg = Kh + (size_t)head * SEQ * HD;  // swizzled [key][64]
  const ushort* klg = Kl + (size_t)head * SEQ * HD;
  const ushort* vtg = Vt + (size_t)head * HD * SEQ;  // swizzled [dim][SEQ]
  const ushort* gp[6];
  ushort* lp[6];
  int gstep[6];
#pragma unroll
  for (int i = 0; i < 6; ++i) {
    int idx = w * 6 + i;
    int arr = idx >> 3, j = idx & 7;
    if (arr == 0) {
      gp[i] = khg + (size_t)(j * 8 + (lane >> 3)) * 64 + (lane & 7) * 8;
      lp[i] = &smem[0 + j * 512];
      gstep[i] = 64 * 64;
    } else if (arr == 1) {
      gp[i] = klg + (size_t)(j * 8 + (lane >> 3)) * 64 + (lane & 7) * 8;
      lp[i] = &smem[8192 + j * 512];
      gstep[i] = 64 * 64;
    } else {
      gp[i] = vtg + (size_t)(j * 8 + (lane >> 3)) * SEQ + (lane & 7) * 8;
      lp[i] = &smem[16384 + j * 512];
      gstep[i] = 64;
    }
  }
#pragma unroll
  for (int i = 0; i < 6; ++i) {
    __builtin_amdgcn_global_load_lds((const GLOBAL_AS unsigned int*)gp[i],
                                     (LDS_AS unsigned int*)lp[i], 16, 0, 0);
    gp[i] += gstep[i];
  }

  // ---- per-lane LDS byte offsets (chunk^key&7 swizzle)
  // K A-frag: row = wk*32+qc (key), dims d*16 + hl*8 + j
  int koff[4];
#pragma unroll
  for (int d = 0; d < 4; ++d)
    koff[d] = ((wk * 32 + qc) * 64 + (((d * 2 + hl) ^ (qc & 7)) & 7) * 8) * 2;
  // V A-frag: row = td*32+qc (dim), keys wk*32 + ks*16 + hl*8 + j
  int voff[2][2];
#pragma unroll
  for (int td = 0; td < 2; ++td)
#pragma unroll
    for (int ks = 0; ks < 2; ++ks)
      voff[td][ks] =
          ((td * 32 + qc) * 64 + (((wk * 4 + ks * 2 + hl) ^ (qc & 7)) & 7) * 8) * 2;

  float m2 = -1e30f, ell = 0.f;
  f32x16 o0, o1;
#pragma unroll
  for (int r = 0; r < 16; ++r) { o0[r] = 0.f; o1[r] = 0.f; }

  auto do_iter = [&](int buf, bool pf) {
    asm volatile("s_waitcnt vmcnt(0)" ::: "memory");
    __syncthreads();
    if (pf) {
#pragma unroll
      for (int i = 0; i < 6; ++i) {
        __builtin_amdgcn_global_load_lds(
            (const GLOBAL_AS unsigned int*)gp[i],
            (LDS_AS unsigned int*)(lp[i] + (buf ^ 1) * 4096), 16, 0, 0);
        gp[i] += gstep[i];
      }
    }
    const char* kh = (const char*)&smem[buf * 4096];
    const char* kl = (const char*)&smem[8192 + buf * 4096];
    const char* vt = (const char*)&smem[16384 + buf * 4096];

    // ---- QK^T swapped: s[key(row)][query(col)], 3-term split precision.
    // Two independent accumulator chains (d 0-1 / d 2-3) halve the dependent
    // MFMA critical path; merged with 16 VALU adds below.
    f32x16 sa, sb;
#pragma unroll
    for (int r = 0; r < 16; ++r) { sa[r] = 0.f; sb[r] = 0.f; }
    __builtin_amdgcn_s_setprio(1);
#pragma unroll
    for (int d = 0; d < 2; ++d) {
      short8 akh = *(const short8*)(kh + koff[d]);
      short8 akl = *(const short8*)(kl + koff[d]);
      sa = __builtin_amdgcn_mfma_f32_32x32x16_bf16(akh, fqh[d], sa, 0, 0, 0);
      sa = __builtin_amdgcn_mfma_f32_32x32x16_bf16(akl, fqh[d], sa, 0, 0, 0);
      sa = __builtin_amdgcn_mfma_f32_32x32x16_bf16(akh, fql[d], sa, 0, 0, 0);
    }
#pragma unroll
    for (int d = 2; d < 4; ++d) {
      short8 akh = *(const short8*)(kh + koff[d]);
      short8 akl = *(const short8*)(kl + koff[d]);
      sb = __builtin_amdgcn_mfma_f32_32x32x16_bf16(akh, fqh[d], sb, 0, 0, 0);
      sb = __builtin_amdgcn_mfma_f32_32x32x16_bf16(akl, fqh[d], sb, 0, 0, 0);
      sb = __builtin_amdgcn_mfma_f32_32x32x16_bf16(akh, fql[d], sb, 0, 0, 0);
    }
    __builtin_amdgcn_s_setprio(0);
    // V fragments (issue early; latency hides under softmax)
    short8 fv00 = *(const short8*)(vt + voff[0][0]);
    short8 fv01 = *(const short8*)(vt + voff[0][1]);
    short8 fv10 = *(const short8*)(vt + voff[1][0]);
    short8 fv11 = *(const short8*)(vt + voff[1][1]);

    f32x16 s;
#pragma unroll
    for (int r = 0; r < 16; ++r) s[r] = sa[r] + sb[r];

    // ---- lazy online softmax (per lane: 1 query, 16 of 32 keys; partner
    //      16 keys live in lane^32)
    float a1 = max3f(s[0], s[1], s[2]);
    float a2 = max3f(s[3], s[4], s[5]);
    float a3 = max3f(s[6], s[7], s[8]);
    float a4 = max3f(s[9], s[10], s[11]);
    float a5 = max3f(s[12], s[13], s[14]);
    float lm = fmaxf(max3f(a1, a2, a3), max3f(a4, a5, s[15]));
    if (!__all(lm <= m2)) {
      float om = __shfl_xor(lm, 32);    // partner half's max (safe pair xchg)
      float vm = fmaxf(lm, om);         // full 32-key row max (pair-uniform)
      float mn = fmaxf(m2, vm + 48.0f); // overshoot margin
      float alpha = exp2f(m2 - mn);
      m2 = mn;
      ell *= alpha;
#pragma unroll
      for (int r = 0; r < 16; ++r) { o0[r] *= alpha; o1[r] *= alpha; }
    }
#pragma unroll
    for (int r = 0; r < 16; ++r) s[r] = exp2f(s[r] - m2);
    float ps = (((s[0] + s[1]) + (s[2] + s[3])) + ((s[4] + s[5]) + (s[6] + s[7]))) +
               (((s[8] + s[9]) + (s[10] + s[11])) + ((s[12] + s[13]) + (s[14] + s[15])));
    ell += ps;

    // ---- P -> PV B-fragments in registers.
    // reg r holds key (r&3)+8*(r>>2)+4*hl; cvt_pk pairs consecutive keys.
    int pk[8];
#pragma unroll
    for (int d = 0; d < 8; ++d) pk[d] = cvt_pk_bf16(s[2 * d], s[2 * d + 1]);
    // k-step 0 (keys 0..15): (w0,w2)=pswap(d0,d2), (w1,w3)=pswap(d1,d3)
    pswap(pk[0], pk[2]);
    pswap(pk[1], pk[3]);
    // k-step 1 (keys 16..31)
    pswap(pk[4], pk[6]);
    pswap(pk[5], pk[7]);
    union { int i[4]; short8 s8; } b0, b1;
    b0.i[0] = pk[0]; b0.i[1] = pk[1]; b0.i[2] = pk[2]; b0.i[3] = pk[3];
    b1.i[0] = pk[4]; b1.i[1] = pk[5]; b1.i[2] = pk[6]; b1.i[3] = pk[7];

    __builtin_amdgcn_s_setprio(1);
    o0 = __builtin_amdgcn_mfma_f32_32x32x16_bf16(fv00, b0.s8, o0, 0, 0, 0);
    o0 = __builtin_amdgcn_mfma_f32_32x32x16_bf16(fv01, b1.s8, o0, 0, 0, 0);
    o1 = __builtin_amdgcn_mfma_f32_32x32x16_bf16(fv10, b0.s8, o1, 0, 0, 0);
    o1 = __builtin_amdgcn_mfma_f32_32x32x16_bf16(fv11, b1.s8, o1, 0, 0, 0);
    __builtin_amdgcn_s_setprio(0);
  };

  for (int kb = 0; kb < SEQ - 128; kb += 128) {
    do_iter(0, true);
    do_iter(1, true);
  }
  do_iter(0, true);
  do_iter(1, false);  // last tile: no dangling DMA at block exit

  // ---- ell: sum the two half-wave partials (lane, lane^32 share a query)
  ell += __shfl_xor(ell, 32);

  // ---- merge the key-split wave pair (flash combine) via LDS.
  // Last compute used buf1; overlay uses buf1's... regions KH1/KL1/VT1 are
  // free (no DMA outstanding, all reads of buf1 done after barrier).
  __syncthreads();
  float* ob = (float*)&smem[4096 + wq * 8192];  // KH1 / KL1: 2048 floats each
  float* mel = (float*)&smem[20480];            // VT1
  if (wk == 1) {
    *(f32x16*)(ob + lane * 32) = o0;
    *(f32x16*)(ob + lane * 32 + 16) = o1;
    mel[wq * 128 + lane] = m2;
    mel[wq * 128 + 64 + lane] = ell;
  }
  __syncthreads();
  if (wk == 0) {
    float m2B = mel[wq * 128 + lane];
    float ellB = mel[wq * 128 + 64 + lane];
    f32x16 p0 = *(const f32x16*)(ob + lane * 32);
    f32x16 p1 = *(const f32x16*)(ob + lane * 32 + 16);
    float mN = fmaxf(m2, m2B);
    float aA = exp2f(m2 - mN), aB = exp2f(m2B - mN);
    float inv = 1.0f / (ell * aA + ellB * aB);
    // out dim for reg r: td*32 + (r&3) + 8*(r>>2) + 4*hl; pairs are contiguous
    ushort* crow = Ch + (size_t)(qb + qc) * EMB + head * 64 + hl * 4;
#pragma unroll
    for (int r = 0; r < 8; ++r) {
      int off = ((2 * r) & 3) + 8 * (r >> 1);
      float v0 = (o0[2 * r] * aA + p0[2 * r] * aB) * inv;
      float v1 = (o0[2 * r + 1] * aA + p0[2 * r + 1] * aB) * inv;
      *(unsigned int*)(crow + off) = (unsigned int)cvt_pk_bf16(v0, v1);
      float w0 = (o1[2 * r] * aA + p1[2 * r] * aB) * inv;
      float w1 = (o1[2 * r + 1] * aA + p1[2 * r + 1] * aB) * inv;
      *(unsigned int*)(crow + 32 + off) = (unsigned int)cvt_pk_bf16(w0, w1);
    }
  }
}

extern "C" void kernel_launch(void* const* d_in, const int* in_sizes, int n_in,
                              void* d_out, int out_size, void* d_ws, size_t ws_size,
                              hipStream_t stream) {
  const float* x = (const float*)d_in[0];       // [4096][768]
  const float* qkv_w = (const float*)d_in[1];   // [2304][768]
  const float* out_w = (const float*)d_in[2];   // [768][768]
  const float* out_b = (const float*)d_in[3];   // [768]
  float* out = (float*)d_out;                   // [4096][768]

  char* p = (char*)d_ws;
  auto carve = [&](size_t bytes) {
    char* q = p;
    p += (bytes + 255) & ~(size_t)255;
    return q;
  };
  const size_t NX = (size_t)SEQ * EMB;       // 3,145,728
  const size_t NQW = (size_t)3 * EMB * EMB;  // 1,769,472
  const size_t NOW = (size_t)EMB * EMB;      // 589,824
  const size_t NQKV = (size_t)NH * SEQ * HD; // 3,145,728

  ushort* xh = (ushort*)carve(NX * 2);
  ushort* xl = (ushort*)carve(NX * 2);
  ushort* qwh = (ushort*)carve(NQW * 2);
  ushort* qwl = (ushort*)carve(NQW * 2);
  ushort* owh = (ushort*)carve(NOW * 2);
  ushort* Qh = (ushort*)carve(NQKV * 2);
  ushort* Ql = (ushort*)carve(NQKV * 2);
  ushort* Kh = (ushort*)carve(NQKV * 2);
  ushort* Kl = (ushort*)carve(NQKV * 2);
  ushort* Vt = (ushort*)carve(NQKV * 2);
  ushort* Ch = (ushort*)carve(NX * 2);

  const int ntot4 = (int)((NX + NQW + NOW) / 4);  // 1,376,256 = 5376 * 256
  split_all<<<dim3(ntot4 / 256), 256, 0, stream>>>(
      x, qkv_w, out_w, xh, xl, qwh, qwl, owh, (int)(NX / 4), (int)(NQW / 4));

  // QKV: M=4096, N=2304, K=768 -> scatter epilogue (K/V swizzled; V 1-term)
  gemm_bt_split<<<dim3(32, 18), 256, 0, stream>>>(
      xh, xl, qwh, qwl, SEQ, 3 * EMB, EMB, 1,
      nullptr, nullptr, Qh, Ql, Kh, Kl, Vt);

  attn_k<<<dim3(SEQ / 64, NH), 256, 0, stream>>>(Qh, Ql, Kh, Kl, Vt, Ch);

  // out proj: M=4096, N=768, K=768, 1-term bf16 + bias -> d_out
  gemm_bt_split<<<dim3(32, 6), 256, 0, stream>>>(
      Ch, Ch, owh, owh, SEQ, EMB, EMB, 2,
      out, out_b, nullptr, nullptr, nullptr, nullptr, nullptr);
}

// Round 5
// 198.264 us; speedup vs baseline: 1.0486x; 1.0486x over previous
//
#include <hip/hip_runtime.h>

typedef __attribute__((ext_vector_type(8))) short short8;
typedef __attribute__((ext_vector_type(4))) float f32x4;
typedef __attribute__((ext_vector_type(16))) float f32x16;
typedef __attribute__((ext_vector_type(2))) unsigned int uint2v;

#define EMB 768
#define SEQ 4096
#define NH 12
#define HD 64
// 8 * log2(e): folds the score scale AND the exp->exp2 conversion into Q
#define QSCALE 11.541560327111707f

#define GLOBAL_AS __attribute__((address_space(1)))
#define LDS_AS __attribute__((address_space(3)))

__device__ inline ushort f2bf(float v) {
  union { float f; unsigned int u; } x; x.f = v;
  unsigned int r = x.u + 0x7fffu + ((x.u >> 16) & 1u);
  return (ushort)(r >> 16);
}
__device__ inline float bf2f(ushort u) {
  union { float f; unsigned int u32; } x; x.u32 = ((unsigned int)u) << 16;
  return x.f;
}

// pack two f32 -> one dword of 2 bf16 (RNE), lo=a hi=b
__device__ inline int cvt_pk_bf16(float a, float b) {
  int r;
  asm("v_cvt_pk_bf16_f32 %0, %1, %2" : "=v"(r) : "v"(a), "v"(b));
  return r;
}
// 3-input max in one VALU op
__device__ inline float max3f(float a, float b, float c) {
  float r;
  asm("v_max3_f32 %0, %1, %2, %3" : "=v"(r) : "v"(a), "v"(b), "v"(c));
  return r;
}
// permlane32_swap via BUILTIN: compiler handles CDNA4 cross-lane hazards
// and tied-register allocation.
__device__ inline void pswap(int& a, int& b) {
  uint2v r = __builtin_amdgcn_permlane32_swap((unsigned)a, (unsigned)b, false, false);
  a = (int)r.x;
  b = (int)r.y;
}

// merged split (float4-vectorized): x -> xh/xl, qkv_w -> qwh/qwl, out_w -> owh
__global__ void split_all(const float* __restrict__ x, const float* __restrict__ qw,
                          const float* __restrict__ ow,
                          ushort* __restrict__ xh, ushort* __restrict__ xl,
                          ushort* __restrict__ qwh, ushort* __restrict__ qwl,
                          ushort* __restrict__ owh, int n14, int n24) {
  int i = blockIdx.x * blockDim.x + threadIdx.x;
  const float4* src;
  ushort4 *dh, *dl;
  int j;
  if (i < n14) {
    src = (const float4*)x; dh = (ushort4*)xh; dl = (ushort4*)xl; j = i;
  } else if (i < n14 + n24) {
    src = (const float4*)qw; dh = (ushort4*)qwh; dl = (ushort4*)qwl; j = i - n14;
  } else {
    j = i - n14 - n24;
    float4 v = ((const float4*)ow)[j];
    ushort4 h = {f2bf(v.x), f2bf(v.y), f2bf(v.z), f2bf(v.w)};
    ((ushort4*)owh)[j] = h;
    return;
  }
  float4 v = src[j];
  ushort4 h = {f2bf(v.x), f2bf(v.y), f2bf(v.z), f2bf(v.w)};
  ushort4 l = {f2bf(v.x - bf2f(h.x)), f2bf(v.y - bf2f(h.y)),
               f2bf(v.z - bf2f(h.z)), f2bf(v.w - bf2f(h.w))};
  dh[j] = h;
  dl[j] = l;
}

// C[m,n] = sum_k A[m,k]*B[n,k] (both K-contiguous), global_load_lds staging,
// double-buffered K-loop. mode 1: QKV scatter; Q,K 3-term; V (bn>=12) 1-term.
// mode 2: 1-term plain bf16, C += bias -> Cout fp32 (out-proj).
__global__ __launch_bounds__(256, 2) void gemm_bt_split(
    const ushort* __restrict__ Ah, const ushort* __restrict__ Al,
    const ushort* __restrict__ Bh, const ushort* __restrict__ Bl,
    int M, int N, int K, int mode,
    float* __restrict__ Cout, const float* __restrict__ bias,
    ushort* __restrict__ Qh, ushort* __restrict__ Ql,
    ushort* __restrict__ Kh, ushort* __restrict__ Kl,
    ushort* __restrict__ Vt) {
  __shared__ ushort smem[2][4 * 128 * 32];  // 2 x 32KB staging buffers

  const int tid = threadIdx.x;
  const int lane = tid & 63;
  const int w = tid >> 6;
  const int wm = w >> 1, wn = w & 1;
  const int col = lane & 15, quad = lane >> 4;
  const int bm = blockIdx.x, bn = blockIdx.y;

  const bool oneterm = (mode == 2) || (mode == 1 && bn >= 12);
  const bool skipdma = oneterm && (w == 1 || w == 3);  // lo tiles unused

  const ushort* gsrc = (w == 0)   ? Ah + (size_t)bm * 128 * K
                       : (w == 1) ? Al + (size_t)bm * 128 * K
                       : (w == 2) ? Bh + (size_t)bn * 128 * K
                                  : Bl + (size_t)bn * 128 * K;
  const int loff = w * 4096;  // matrix offset inside a buffer
  const ushort* g0 = gsrc + (size_t)(lane >> 2) * K + (lane & 3) * 8;

  f32x4 acc[4][4];
  const f32x4 zz = {0.f, 0.f, 0.f, 0.f};
#pragma unroll
  for (int i = 0; i < 4; ++i)
#pragma unroll
    for (int j = 0; j < 4; ++j) acc[i][j] = zz;

#define GSTAGE(b, kt)                                                       \
  if (!skipdma) {                                                           \
    _Pragma("unroll") for (int i = 0; i < 8; ++i) {                         \
      __builtin_amdgcn_global_load_lds(                                     \
          (const GLOBAL_AS unsigned int*)(g0 + (size_t)i * 16 * K + (kt)),  \
          (LDS_AS unsigned int*)(&smem[b][loff + i * 512]), 16, 0, 0);      \
    }                                                                       \
  }

  GSTAGE(0, 0);
  const int nk = K / 32;
  for (int it = 0; it < nk; ++it) {
    const int buf = it & 1;
    asm volatile("s_waitcnt vmcnt(0)" ::: "memory");
    __syncthreads();
    if (it + 1 < nk) GSTAGE(buf ^ 1, (it + 1) * 32);

    const ushort* sAh = &smem[buf][0];
    const ushort* sAl = &smem[buf][4096];
    const ushort* sBh = &smem[buf][8192];
    const ushort* sBl = &smem[buf][12288];

    if (oneterm) {
      short8 fah[4], fbh[4];
#pragma unroll
      for (int t = 0; t < 4; ++t) {
        fah[t] = *(const short8*)(&sAh[(wm * 64 + t * 16 + col) * 32 + quad * 8]);
        fbh[t] = *(const short8*)(&sBh[(wn * 64 + t * 16 + col) * 32 + quad * 8]);
      }
#pragma unroll
      for (int tm = 0; tm < 4; ++tm)
#pragma unroll
        for (int tn = 0; tn < 4; ++tn)
          acc[tm][tn] = __builtin_amdgcn_mfma_f32_16x16x32_bf16(fah[tm], fbh[tn], acc[tm][tn], 0, 0, 0);
    } else {
      short8 fah[4], fal[4], fbh[4], fbl[4];
#pragma unroll
      for (int t = 0; t < 4; ++t) {
        int ra = (wm * 64 + t * 16 + col) * 32 + quad * 8;
        fah[t] = *(const short8*)(&sAh[ra]);
        fal[t] = *(const short8*)(&sAl[ra]);
        int rb = (wn * 64 + t * 16 + col) * 32 + quad * 8;
        fbh[t] = *(const short8*)(&sBh[rb]);
        fbl[t] = *(const short8*)(&sBl[rb]);
      }
#pragma unroll
      for (int tm = 0; tm < 4; ++tm)
#pragma unroll
        for (int tn = 0; tn < 4; ++tn) {
          acc[tm][tn] = __builtin_amdgcn_mfma_f32_16x16x32_bf16(fah[tm], fbh[tn], acc[tm][tn], 0, 0, 0);
          acc[tm][tn] = __builtin_amdgcn_mfma_f32_16x16x32_bf16(fah[tm], fbl[tn], acc[tm][tn], 0, 0, 0);
          acc[tm][tn] = __builtin_amdgcn_mfma_f32_16x16x32_bf16(fal[tm], fbh[tn], acc[tm][tn], 0, 0, 0);
        }
    }
  }

  const int m_base = bm * 128 + wm * 64;
  const int n_base = bn * 128 + wn * 64;

  if (mode != 1) {
#pragma unroll
    for (int tm = 0; tm < 4; ++tm)
#pragma unroll
      for (int tn = 0; tn < 4; ++tn) {
        int gn = n_base + tn * 16 + col;
        float b = bias[gn];
#pragma unroll
        for (int rr = 0; rr < 4; ++rr) {
          int gm = m_base + tm * 16 + quad * 4 + rr;
          Cout[(size_t)gm * N + gn] = acc[tm][tn][rr] + b;
        }
      }
  } else {
    int reg = bn / 6;  // 0:Q 1:K 2:V (uniform per block)
    if (reg < 2) {
#pragma unroll
      for (int tm = 0; tm < 4; ++tm)
#pragma unroll
        for (int tn = 0; tn < 4; ++tn) {
          int el = (bn % 6) * 128 + wn * 64 + tn * 16 + col;  // 0..767
          int hh = el >> 6, dd = el & 63;
#pragma unroll
          for (int rr = 0; rr < 4; ++rr) {
            int gm = m_base + tm * 16 + quad * 4 + rr;
            float v = acc[tm][tn][rr];
            if (reg == 0) {
              v *= QSCALE;
              ushort hi = f2bf(v);
              size_t idx = ((size_t)hh * SEQ + gm) * HD + dd;  // Q unswizzled
              Qh[idx] = hi;
              Ql[idx] = f2bf(v - bf2f(hi));
            } else {
              // K swizzled: chunk' = chunk ^ (key&7) for attn's DMA image
              ushort hi = f2bf(v);
              int pc = ((dd >> 3) ^ (gm & 7)) & 7;
              size_t idx = ((size_t)hh * SEQ + gm) * HD + pc * 8 + (dd & 7);
              Kh[idx] = hi;
              Kl[idx] = f2bf(v - bf2f(hi));
            }
          }
        }
    } else {
      // ---- V: LDS transpose -> coalesced swizzled stores ----
      __syncthreads();
      ushort* vt_tile = &smem[0][0];  // 128*128 ushort = 32KB
#pragma unroll
      for (int tm = 0; tm < 4; ++tm)
#pragma unroll
        for (int tn = 0; tn < 4; ++tn) {
          int el = wn * 64 + tn * 16 + col;
#pragma unroll
          for (int rr = 0; rr < 4; ++rr) {
            int seq = wm * 64 + tm * 16 + quad * 4 + rr;
            int cc = (((seq >> 3) & 7) ^ (el & 7)) & 7;
            vt_tile[el * 128 + (seq & 64) + cc * 8 + (seq & 7)] = f2bf(acc[tm][tn][rr]);
          }
        }
      __syncthreads();
      int el = tid >> 1;
      int elg = (bn % 6) * 128 + el;
      int hh = elg >> 6, dd = elg & 63;
      ushort* grow = Vt + (size_t)(hh * HD + dd) * SEQ + bm * 128;
#pragma unroll
      for (int i = 0; i < 8; ++i) {
        int c = ((tid & 1) * 8 + i + el) & 15;
        *(uint4*)(grow + c * 8) = *(const uint4*)(&vt_tile[el * 128 + c * 8]);
      }
    }
  }
}

// Flash attention R16 = R14 (verified 144us structure) + XCD-chunked block
// swizzle (T1) + max3 row-max + guarded final DMA. setprio and the split-s
// experiment (R15, regressed) are reverted.
// Swizzle rationale: with round-robin XCD placement each XCD's ~96 resident
// blocks span all 12 heads (56MB K/V working set vs 4MB L2 -> ~0 L2 reuse,
// all streams served from L3 at ~500cy). Chunked mapping gives each XCD 96
// consecutive blocks (1.5 heads) advancing through SEQ in near-lockstep ->
// the K/V tile window L2-hits for ~63 of 64 q-blocks.
__global__ __launch_bounds__(256, 3) void attn_k(
    const ushort* __restrict__ Qh, const ushort* __restrict__ Ql,
    const ushort* __restrict__ Kh, const ushort* __restrict__ Kl,
    const ushort* __restrict__ Vt, ushort* __restrict__ Ch) {
  // regions (ushort idx): KH[2][4096] @0, KL[2][4096] @8192, VT[2][4096] @16384
  __shared__ __attribute__((aligned(128))) ushort smem[6 * 4096];  // 48KB

  const int tid = threadIdx.x, lane = tid & 63, w = tid >> 6;
  const int wq = w >> 1, wk = w & 1;
  const int qc = lane & 31, hl = lane >> 5;

  // ---- XCD-chunked swizzle: 768 blocks, 8 XCDs, 96/chunk (768%8==0 ->
  // bijective). lid%8 = XCD -> chunk (lid%8)*96 + lid/8.
  const int lid = blockIdx.x + (int)(gridDim.x) * blockIdx.y;
  const int wid = (lid & 7) * 96 + (lid >> 3);
  const int head = wid >> 6;          // 64 q-blocks per head
  const int qb = (wid & 63) * 64 + wq * 32;

  // ---- Q fragments (B-operand): B[n=query qc][k = d*16 + hl*8 + j]
  const ushort* qh_base = Qh + ((size_t)head * SEQ + qb + qc) * HD + hl * 8;
  const ushort* ql_base = Ql + ((size_t)head * SEQ + qb + qc) * HD + hl * 8;
  short8 fqh[4], fql[4];
#pragma unroll
  for (int d = 0; d < 4; ++d) {
    fqh[d] = *(const short8*)(qh_base + d * 16);
    fql[d] = *(const short8*)(ql_base + d * 16);
  }

  // ---- staging (identical DMA pattern to R14)
  const ushort* khg = Kh + (size_t)head * SEQ * HD;  // swizzled [key][64]
  const ushort* klg = Kl + (size_t)head * SEQ * HD;
  const ushort* vtg = Vt + (size_t)head * HD * SEQ;  // swizzled [dim][SEQ]
  const ushort* gp[6];
  ushort* lp[6];
  int gstep[6];
#pragma unroll
  for (int i = 0; i < 6; ++i) {
    int idx = w * 6 + i;
    int arr = idx >> 3, j = idx & 7;
    if (arr == 0) {
      gp[i] = khg + (size_t)(j * 8 + (lane >> 3)) * 64 + (lane & 7) * 8;
      lp[i] = &smem[0 + j * 512];
      gstep[i] = 64 * 64;
    } else if (arr == 1) {
      gp[i] = klg + (size_t)(j * 8 + (lane >> 3)) * 64 + (lane & 7) * 8;
      lp[i] = &smem[8192 + j * 512];
      gstep[i] = 64 * 64;
    } else {
      gp[i] = vtg + (size_t)(j * 8 + (lane >> 3)) * SEQ + (lane & 7) * 8;
      lp[i] = &smem[16384 + j * 512];
      gstep[i] = 64;
    }
  }
#pragma unroll
  for (int i = 0; i < 6; ++i) {
    __builtin_amdgcn_global_load_lds((const GLOBAL_AS unsigned int*)gp[i],
                                     (LDS_AS unsigned int*)lp[i], 16, 0, 0);
    gp[i] += gstep[i];
  }

  // ---- per-lane LDS byte offsets (chunk^key&7 swizzle)
  // K A-frag: row = wk*32+qc (key), dims d*16 + hl*8 + j
  int koff[4];
#pragma unroll
  for (int d = 0; d < 4; ++d)
    koff[d] = ((wk * 32 + qc) * 64 + (((d * 2 + hl) ^ (qc & 7)) & 7) * 8) * 2;
  // V A-frag: row = td*32+qc (dim), keys wk*32 + ks*16 + hl*8 + j
  int voff[2][2];
#pragma unroll
  for (int td = 0; td < 2; ++td)
#pragma unroll
    for (int ks = 0; ks < 2; ++ks)
      voff[td][ks] =
          ((td * 32 + qc) * 64 + (((wk * 4 + ks * 2 + hl) ^ (qc & 7)) & 7) * 8) * 2;

  float m2 = -1e30f, ell = 0.f;
  f32x16 o0, o1;
#pragma unroll
  for (int r = 0; r < 16; ++r) { o0[r] = 0.f; o1[r] = 0.f; }

  auto do_iter = [&](int buf, bool pf) {
    asm volatile("s_waitcnt vmcnt(0)" ::: "memory");
    __syncthreads();
    if (pf) {
#pragma unroll
      for (int i = 0; i < 6; ++i) {
        __builtin_amdgcn_global_load_lds(
            (const GLOBAL_AS unsigned int*)gp[i],
            (LDS_AS unsigned int*)(lp[i] + (buf ^ 1) * 4096), 16, 0, 0);
        gp[i] += gstep[i];
      }
    }
    const char* kh = (const char*)&smem[buf * 4096];
    const char* kl = (const char*)&smem[8192 + buf * 4096];
    const char* vt = (const char*)&smem[16384 + buf * 4096];

    // ---- QK^T swapped: s[key(row)][query(col)], 3-term split precision
    f32x16 s;
#pragma unroll
    for (int r = 0; r < 16; ++r) s[r] = 0.f;
#pragma unroll
    for (int d = 0; d < 4; ++d) {
      short8 akh = *(const short8*)(kh + koff[d]);
      short8 akl = *(const short8*)(kl + koff[d]);
      s = __builtin_amdgcn_mfma_f32_32x32x16_bf16(akh, fqh[d], s, 0, 0, 0);
      s = __builtin_amdgcn_mfma_f32_32x32x16_bf16(akl, fqh[d], s, 0, 0, 0);
      s = __builtin_amdgcn_mfma_f32_32x32x16_bf16(akh, fql[d], s, 0, 0, 0);
    }
    // V fragments (issue early; latency hides under softmax)
    short8 fv00 = *(const short8*)(vt + voff[0][0]);
    short8 fv01 = *(const short8*)(vt + voff[0][1]);
    short8 fv10 = *(const short8*)(vt + voff[1][0]);
    short8 fv11 = *(const short8*)(vt + voff[1][1]);

    // ---- lazy online softmax (per lane: 1 query, 16 of 32 keys; partner
    //      16 keys live in lane^32)
    float a1 = max3f(s[0], s[1], s[2]);
    float a2 = max3f(s[3], s[4], s[5]);
    float a3 = max3f(s[6], s[7], s[8]);
    float a4 = max3f(s[9], s[10], s[11]);
    float a5 = max3f(s[12], s[13], s[14]);
    float lm = fmaxf(max3f(a1, a2, a3), max3f(a4, a5, s[15]));
    if (!__all(lm <= m2)) {
      float om = __shfl_xor(lm, 32);    // partner half's max (safe pair xchg)
      float vm = fmaxf(lm, om);         // full 32-key row max (pair-uniform)
      float mn = fmaxf(m2, vm + 48.0f); // overshoot margin
      float alpha = exp2f(m2 - mn);
      m2 = mn;
      ell *= alpha;
#pragma unroll
      for (int r = 0; r < 16; ++r) { o0[r] *= alpha; o1[r] *= alpha; }
    }
#pragma unroll
    for (int r = 0; r < 16; ++r) s[r] = exp2f(s[r] - m2);
    float ps = (((s[0] + s[1]) + (s[2] + s[3])) + ((s[4] + s[5]) + (s[6] + s[7]))) +
               (((s[8] + s[9]) + (s[10] + s[11])) + ((s[12] + s[13]) + (s[14] + s[15])));
    ell += ps;

    // ---- P -> PV B-fragments in registers.
    // reg r holds key (r&3)+8*(r>>2)+4*hl; cvt_pk pairs consecutive keys.
    int pk[8];
#pragma unroll
    for (int d = 0; d < 8; ++d) pk[d] = cvt_pk_bf16(s[2 * d], s[2 * d + 1]);
    // k-step 0 (keys 0..15): (w0,w2)=pswap(d0,d2), (w1,w3)=pswap(d1,d3)
    pswap(pk[0], pk[2]);
    pswap(pk[1], pk[3]);
    // k-step 1 (keys 16..31)
    pswap(pk[4], pk[6]);
    pswap(pk[5], pk[7]);
    union { int i[4]; short8 s8; } b0, b1;
    b0.i[0] = pk[0]; b0.i[1] = pk[1]; b0.i[2] = pk[2]; b0.i[3] = pk[3];
    b1.i[0] = pk[4]; b1.i[1] = pk[5]; b1.i[2] = pk[6]; b1.i[3] = pk[7];

    o0 = __builtin_amdgcn_mfma_f32_32x32x16_bf16(fv00, b0.s8, o0, 0, 0, 0);
    o0 = __builtin_amdgcn_mfma_f32_32x32x16_bf16(fv01, b1.s8, o0, 0, 0, 0);
    o1 = __builtin_amdgcn_mfma_f32_32x32x16_bf16(fv10, b0.s8, o1, 0, 0, 0);
    o1 = __builtin_amdgcn_mfma_f32_32x32x16_bf16(fv11, b1.s8, o1, 0, 0, 0);
  };

  for (int kb = 0; kb < SEQ - 128; kb += 128) {
    do_iter(0, true);
    do_iter(1, true);
  }
  do_iter(0, true);
  do_iter(1, false);  // last tile: no dangling DMA at block exit

  // ---- ell: sum the two half-wave partials (lane, lane^32 share a query)
  ell += __shfl_xor(ell, 32);

  // ---- merge the key-split wave pair (flash combine) via LDS.
  __syncthreads();
  float* ob = (float*)&smem[4096 + wq * 8192];  // KH1 / KL1: 2048 floats each
  float* mel = (float*)&smem[20480];            // VT1
  if (wk == 1) {
    *(f32x16*)(ob + lane * 32) = o0;
    *(f32x16*)(ob + lane * 32 + 16) = o1;
    mel[wq * 128 + lane] = m2;
    mel[wq * 128 + 64 + lane] = ell;
  }
  __syncthreads();
  if (wk == 0) {
    float m2B = mel[wq * 128 + lane];
    float ellB = mel[wq * 128 + 64 + lane];
    f32x16 p0 = *(const f32x16*)(ob + lane * 32);
    f32x16 p1 = *(const f32x16*)(ob + lane * 32 + 16);
    float mN = fmaxf(m2, m2B);
    float aA = exp2f(m2 - mN), aB = exp2f(m2B - mN);
    float inv = 1.0f / (ell * aA + ellB * aB);
    // out dim for reg r: td*32 + (r&3) + 8*(r>>2) + 4*hl; pairs are contiguous
    ushort* crow = Ch + (size_t)(qb + qc) * EMB + head * 64 + hl * 4;
#pragma unroll
    for (int r = 0; r < 8; ++r) {
      int off = ((2 * r) & 3) + 8 * (r >> 1);
      float v0 = (o0[2 * r] * aA + p0[2 * r] * aB) * inv;
      float v1 = (o0[2 * r + 1] * aA + p0[2 * r + 1] * aB) * inv;
      *(unsigned int*)(crow + off) = (unsigned int)cvt_pk_bf16(v0, v1);
      float w0 = (o1[2 * r] * aA + p1[2 * r] * aB) * inv;
      float w1 = (o1[2 * r + 1] * aA + p1[2 * r + 1] * aB) * inv;
      *(unsigned int*)(crow + 32 + off) = (unsigned int)cvt_pk_bf16(w0, w1);
    }
  }
}

extern "C" void kernel_launch(void* const* d_in, const int* in_sizes, int n_in,
                              void* d_out, int out_size, void* d_ws, size_t ws_size,
                              hipStream_t stream) {
  const float* x = (const float*)d_in[0];       // [4096][768]
  const float* qkv_w = (const float*)d_in[1];   // [2304][768]
  const float* out_w = (const float*)d_in[2];   // [768][768]
  const float* out_b = (const float*)d_in[3];   // [768]
  float* out = (float*)d_out;                   // [4096][768]

  char* p = (char*)d_ws;
  auto carve = [&](size_t bytes) {
    char* q = p;
    p += (bytes + 255) & ~(size_t)255;
    return q;
  };
  const size_t NX = (size_t)SEQ * EMB;       // 3,145,728
  const size_t NQW = (size_t)3 * EMB * EMB;  // 1,769,472
  const size_t NOW = (size_t)EMB * EMB;      // 589,824
  const size_t NQKV = (size_t)NH * SEQ * HD; // 3,145,728

  ushort* xh = (ushort*)carve(NX * 2);
  ushort* xl = (ushort*)carve(NX * 2);
  ushort* qwh = (ushort*)carve(NQW * 2);
  ushort* qwl = (ushort*)carve(NQW * 2);
  ushort* owh = (ushort*)carve(NOW * 2);
  ushort* Qh = (ushort*)carve(NQKV * 2);
  ushort* Ql = (ushort*)carve(NQKV * 2);
  ushort* Kh = (ushort*)carve(NQKV * 2);
  ushort* Kl = (ushort*)carve(NQKV * 2);
  ushort* Vt = (ushort*)carve(NQKV * 2);
  ushort* Ch = (ushort*)carve(NX * 2);

  const int ntot4 = (int)((NX + NQW + NOW) / 4);  // 1,376,256 = 5376 * 256
  split_all<<<dim3(ntot4 / 256), 256, 0, stream>>>(
      x, qkv_w, out_w, xh, xl, qwh, qwl, owh, (int)(NX / 4), (int)(NQW / 4));

  // QKV: M=4096, N=2304, K=768 -> scatter epilogue (K/V swizzled; V 1-term)
  gemm_bt_split<<<dim3(32, 18), 256, 0, stream>>>(
      xh, xl, qwh, qwl, SEQ, 3 * EMB, EMB, 1,
      nullptr, nullptr, Qh, Ql, Kh, Kl, Vt);

  attn_k<<<dim3(SEQ / 64, NH), 256, 0, stream>>>(Qh, Ql, Kh, Kl, Vt, Ch);

  // out proj: M=4096, N=768, K=768, 1-term bf16 + bias -> d_out
  gemm_bt_split<<<dim3(32, 6), 256, 0, stream>>>(
      Ch, Ch, owh, owh, SEQ, EMB, EMB, 2,
      out, out_b, nullptr, nullptr, nullptr, nullptr, nullptr);
}